// Round 10
// baseline (225.045 us; speedup 1.0000x reference)
//
#include <hip/hip_runtime.h>
#include <hip/hip_bf16.h>
#include <stdint.h>

#define H 12
#define S 2048
#define BATCH 2
#define DM 768
#define DH 64

typedef __attribute__((ext_vector_type(4))) float f32x4;
typedef __attribute__((ext_vector_type(4))) short s16x4;
typedef __attribute__((ext_vector_type(8))) short s16x8;

static __device__ __forceinline__ short f2bf(float f) {
  uint32_t u = __builtin_bit_cast(uint32_t, f);
  uint32_t r = (u + 0x7FFFu + ((u >> 16) & 1u)) >> 16;
  return (short)r;
}

static __device__ __forceinline__ s16x8 cvt8(f32x4 a, f32x4 b) {
  s16x8 r;
  r[0] = f2bf(a[0]); r[1] = f2bf(a[1]); r[2] = f2bf(a[2]); r[3] = f2bf(a[3]);
  r[4] = f2bf(b[0]); r[5] = f2bf(b[1]); r[6] = f2bf(b[2]); r[7] = f2bf(b[3]);
  return r;
}

static __device__ __forceinline__ f32x4 zero4() {
  f32x4 v; v[0] = 0.f; v[1] = 0.f; v[2] = 0.f; v[3] = 0.f; return v;
}

#define GLD_LDS16(g, l)                                                              \
  __builtin_amdgcn_global_load_lds((__attribute__((address_space(1))) const void*)(g), \
                                   (__attribute__((address_space(3))) void*)(l), 16, 0, 0)

#define WAITV(N) asm volatile("s_waitcnt vmcnt(" #N ")" ::: "memory")
#define WAITL0() asm volatile("s_waitcnt lgkmcnt(0)" ::: "memory")
#define BAR() __builtin_amdgcn_s_barrier()
#define FENCE() asm volatile("" ::: "memory")

// ---------------------------------------------------------------------------
// Kernel 0: weights -> bf16, transposed.
// wt  : [3][H][64 n][768 k]  (W_{Q,K,V}^T per head)
// wot : [H][768 m][64 d]     (W_O^T per head)
// ---------------------------------------------------------------------------
__global__ __launch_bounds__(256) void k_prep(const float* __restrict__ wq,
                                              const float* __restrict__ wk,
                                              const float* __restrict__ wv,
                                              const float* __restrict__ wo,
                                              short* __restrict__ wt,
                                              short* __restrict__ wot) {
  int tid = blockIdx.x * 256 + threadIdx.x;
  int nthr = gridDim.x * 256;
  const int NQKV = 3 * H * DM * DH;
  for (int i = tid; i < NQKV; i += nthr) {
    int n = i & 63;
    int k = (i >> 6) % DM;
    int rest = (i >> 6) / DM;  // t*H + h
    int h = rest % H;
    int t = rest / H;
    const float* src = (t == 0 ? wq : t == 1 ? wk : wv);
    float v = src[((size_t)h * DM + k) * DH + n];
    wt[(((size_t)t * H + h) * DH + n) * DM + k] = f2bf(v);
  }
  const int NO = H * DH * DM;
  for (int i = tid; i < NO; i += nthr) {
    int m = i % DM;
    int d = (i / DM) % DH;
    int h = i / (DM * DH);
    wot[((size_t)h * DM + m) * DH + d] = f2bf(wo[((size_t)h * DH + d) * DM + m]);
  }
}

// ---------------------------------------------------------------------------
// Kernel 1: Q/K/V projection — depth-2 counted pipeline, triple-buffered LDS.
// grid = 2304, region-co-scheduled mapping.
// ---------------------------------------------------------------------------
__global__ __launch_bounds__(256) void k_proj(
    const float* __restrict__ xq, const float* __restrict__ xk, const float* __restrict__ xv,
    const float* __restrict__ bq, const float* __restrict__ bk, const float* __restrict__ bv,
    const short* __restrict__ wt,
    short* __restrict__ q_ws, short* __restrict__ k_ws, short* __restrict__ vt_ws) {
  const int u = blockIdx.x;             // 0..2303
  const int xcd = u & 7;
  const int slot = u >> 3;              // 0..287
  const int r = (slot / 12) * 8 + xcd;  // 0..191 region (t,b,qtile)
  const int h = slot % 12;
  const int t = r / 64;
  const int rb = r % 64;
  const int b = rb >> 5;
  const int q0 = (rb & 31) * 64;

  const float* x = (t == 0 ? xq : t == 1 ? xk : xv);
  const float* xbase = x + ((size_t)(b * S + q0) * H + h) * DM;     // row stride H*DM
  const short* wbase = wt + ((size_t)t * H + h) * (size_t)DH * DM;  // [64 n][768 k]

  __shared__ float A_sm[3][64 * 64];  // 3 x 16 KB, swizzled content
  __shared__ short W_sm[3][64 * 64];  // 3 x 8 KB, swizzled content

  const int tid = threadIdx.x;
  const int w = tid >> 6;
  const int l = tid & 63;
  const int g = l >> 4;
  const int m16 = l & 15;
  const int wswz = ((l & 7) ^ (l >> 3)) * 8;  // W source col (shorts)

  const int arow_st = (l >> 4);
  const int apb = (l & 15) * 16;

  f32x4 acc[4];
#pragma unroll
  for (int nt = 0; nt < 4; ++nt) acc[nt] = zero4();

#define PROJ_STAGE(sel, kc)                                                          \
  do {                                                                               \
    _Pragma("unroll") for (int i = 0; i < 4; ++i) {                                  \
      int row = (w * 4 + i) * 4 + arow_st;                                           \
      int colf = (apb ^ ((row & 7) << 4)) >> 2;                                      \
      GLD_LDS16(xbase + (size_t)row * (H * DM) + (kc) * 64 + colf,                   \
                (char*)A_sm + (sel) * 16384 + (w * 4 + i) * 1024);                   \
    }                                                                                \
    _Pragma("unroll") for (int i = 0; i < 2; ++i) {                                  \
      int ch = w * 2 + i;                                                            \
      int n = ch * 8 + (l >> 3);                                                     \
      GLD_LDS16(wbase + (size_t)n * DM + (kc) * 64 + wswz,                           \
                (char*)W_sm + (sel) * 8192 + ch * 1024);                             \
    }                                                                                \
  } while (0)

#define PROJ_COMPUTE(sel)                                                            \
  do {                                                                               \
    const char* Ab = (const char*)A_sm + (sel) * 16384;                              \
    const char* Wb = (const char*)W_sm + (sel) * 8192;                               \
    int arow = 16 * w + m16;                                                         \
    int asw = (arow & 7) << 4;                                                       \
    _Pragma("unroll") for (int c = 0; c < 2; ++c) {                                  \
      f32x4 a0 = *(const f32x4*)(Ab + arow * 256 + ((32 * g + 128 * c) ^ asw));      \
      f32x4 a1 = *(const f32x4*)(Ab + arow * 256 + ((32 * g + 128 * c + 16) ^ asw)); \
      s16x8 afr = cvt8(a0, a1);                                                      \
      int krow = 8 * g + 32 * c;                                                     \
      _Pragma("unroll") for (int nt = 0; nt < 4; ++nt) {                             \
        int n = m16 + 16 * nt;                                                       \
        s16x8 bfr = *(const s16x8*)(Wb + ((n * 128 + krow * 2) ^ ((n & 7) << 4)));   \
        acc[nt] = __builtin_amdgcn_mfma_f32_16x16x32_bf16(afr, bfr, acc[nt], 0, 0, 0); \
      }                                                                              \
    }                                                                                \
  } while (0)

  PROJ_STAGE(0, 0);
  PROJ_STAGE(1, 1);  // 12 vmem in flight
#pragma unroll
  for (int kc = 0; kc < 12; ++kc) {
    const int sel = kc % 3;
    if (kc < 10) {
      PROJ_STAGE((kc + 2) % 3, kc + 2);
      WAITV(12);  // chunk kc landed; kc+1, kc+2 stay in flight
    } else if (kc == 10) {
      WAITV(6);   // chunk 10 landed; chunk 11 stays
    } else {
      WAITV(0);
    }
    BAR(); FENCE();
    PROJ_COMPUTE(sel);
    WAITL0(); BAR(); FENCE();
  }

  const float* bias = (t == 0 ? bq : t == 1 ? bk : bv) + h * DH;
  if (t < 2) {
    short* dst = (t == 0 ? q_ws : k_ws) + (size_t)(b * H + h) * S * DH;
#pragma unroll
    for (int nt = 0; nt < 4; ++nt) {
      int n = 16 * nt + m16;
      float bb = bias[n];
#pragma unroll
      for (int r2 = 0; r2 < 4; ++r2) {
        int q = q0 + 16 * w + 4 * g + r2;
        dst[(size_t)q * DH + n] = f2bf(acc[nt][r2] + bb);
      }
    }
  } else {
    short* dst = vt_ws + (size_t)(b * H + h) * DH * S;  // [d][kv]
#pragma unroll
    for (int nt = 0; nt < 4; ++nt) {
      int n = 16 * nt + m16;  // d
      float bb = bias[n];
#pragma unroll
      for (int r2 = 0; r2 < 4; ++r2) {
        int q = q0 + 16 * w + 4 * g + r2;  // kv
        dst[(size_t)n * S + q] = f2bf(acc[nt][r2] + bb);
      }
    }
  }
}

// ---------------------------------------------------------------------------
// Kernel 2: causal flash attention FUSED with output projection.
// Epilogue: results bounced through swizzled LDS obuf; global store is
// LINEAR (read side un-swizzles; rule 21: both-sides-or-neither).
// ---------------------------------------------------------------------------
__global__ __launch_bounds__(256) void k_attn_o(const short* __restrict__ q_ws,
                                                const short* __restrict__ k_ws,
                                                const short* __restrict__ vt_ws,
                                                const short* __restrict__ wot,
                                                const float* __restrict__ bo,
                                                float* __restrict__ out) {
  const int u = blockIdx.x;         // 0..767
  const int xcd = u & 7;
  const int slot = u >> 3;          // 0..95
  const int r = (slot / 12) * 8 + xcd;  // 0..63 region (b,qtile)
  const int h = slot % 12;
  const int b = r >> 5;
  const int qtile = 31 - (r & 31);  // heavy (late) q-tiles first
  const int q0 = qtile * 64;

  const size_t sl = (size_t)(b * H + h) * S * DH;
  const short* qs = q_ws + sl;
  const short* ks = k_ws + sl;
  const short* vs = vt_ws + sl;  // [64 d][2048 kv]

  __shared__ short K_sm[2][64 * 64];
  __shared__ short V_sm[2][64 * 64];
  __shared__ short P_sm[4][16 * 72];

  const int tid = threadIdx.x;
  const int w = tid >> 6;
  const int l = tid & 63;
  const int g = l >> 4;
  const int m16 = l & 15;
  const int swz_src = ((l & 7) ^ (l >> 3)) * 8;

#define ATTN_STAGE(sel, kv0)                                                         \
  do {                                                                               \
    _Pragma("unroll") for (int i = 0; i < 2; ++i) {                                  \
      int ch = w * 2 + i;                                                            \
      int row = ch * 8 + (l >> 3);                                                   \
      GLD_LDS16(ks + (size_t)((kv0) + row) * DH + swz_src,                           \
                (char*)K_sm + (sel) * 8192 + ch * 1024);                             \
      GLD_LDS16(vs + (size_t)row * S + (kv0) + swz_src,                              \
                (char*)V_sm + (sel) * 8192 + ch * 1024);                             \
    }                                                                                \
  } while (0)

  s16x8 qf[2];
  {
    int q = q0 + 16 * w + m16;
    qf[0] = *(const s16x8*)(qs + (size_t)q * DH + 8 * g);
    qf[1] = *(const s16x8*)(qs + (size_t)q * DH + 8 * g + 32);
  }

  f32x4 o_acc[4];
  float m_run[4], l_run[4], alpha[4];
#pragma unroll
  for (int nt = 0; nt < 4; ++nt) o_acc[nt] = zero4();
#pragma unroll
  for (int rr = 0; rr < 4; ++rr) { m_run[rr] = -3.0e38f; l_run[rr] = 0.f; }

  const int ktiles = qtile + 1;
  ATTN_STAGE(0, 0);  // 4 in flight
  for (int kt = 0; kt < ktiles; ++kt) {
    const int kv0 = kt * 64;
    const int cur = kt & 1;
    if (kt + 1 < ktiles) {
      ATTN_STAGE(cur ^ 1, kv0 + 64);
      WAITV(4);
    } else {
      WAITV(0);
    }
    BAR(); FENCE();

    // S = Q K^T
    f32x4 sacc[4];
#pragma unroll
    for (int nt = 0; nt < 4; ++nt) sacc[nt] = zero4();
#pragma unroll
    for (int c = 0; c < 2; ++c) {
      int kr2 = (8 * g + 32 * c) * 2;
#pragma unroll
      for (int nt = 0; nt < 4; ++nt) {
        int row = m16 + 16 * nt;  // kv local
        s16x8 kf = *(const s16x8*)((const char*)K_sm + cur * 8192 +
                                   ((row * 128 + kr2) ^ ((row & 7) << 4)));
        sacc[nt] = __builtin_amdgcn_mfma_f32_16x16x32_bf16(qf[c], kf, sacc[nt], 0, 0, 0);
      }
    }
    // scale + causal mask
    float sv[4][4];
#pragma unroll
    for (int nt = 0; nt < 4; ++nt) {
      int kv = kv0 + 16 * nt + m16;
#pragma unroll
      for (int rr = 0; rr < 4; ++rr) {
        int q = q0 + 16 * w + 4 * g + rr;
        float s = sacc[nt][rr] * 0.125f;
        sv[nt][rr] = (kv > q) ? -1.0e30f : s;
      }
    }
    // online softmax
#pragma unroll
    for (int rr = 0; rr < 4; ++rr) {
      float tm = fmaxf(fmaxf(sv[0][rr], sv[1][rr]), fmaxf(sv[2][rr], sv[3][rr]));
      tm = fmaxf(tm, __shfl_xor(tm, 1));
      tm = fmaxf(tm, __shfl_xor(tm, 2));
      tm = fmaxf(tm, __shfl_xor(tm, 4));
      tm = fmaxf(tm, __shfl_xor(tm, 8));
      float mn = fmaxf(m_run[rr], tm);
      alpha[rr] = __expf(m_run[rr] - mn);
      m_run[rr] = mn;
      float rs = 0.f;
#pragma unroll
      for (int nt = 0; nt < 4; ++nt) {
        float p = __expf(sv[nt][rr] - mn);
        sv[nt][rr] = p;
        rs += p;
      }
      rs += __shfl_xor(rs, 1);
      rs += __shfl_xor(rs, 2);
      rs += __shfl_xor(rs, 4);
      rs += __shfl_xor(rs, 8);
      l_run[rr] = l_run[rr] * alpha[rr] + rs;
    }
    // P -> bf16 -> per-wave LDS bounce
#pragma unroll
    for (int nt = 0; nt < 4; ++nt)
#pragma unroll
      for (int rr = 0; rr < 4; ++rr)
        P_sm[w][(4 * g + rr) * 72 + 16 * nt + m16] = f2bf(sv[nt][rr]);
    // rescale O
#pragma unroll
    for (int nt = 0; nt < 4; ++nt)
#pragma unroll
      for (int rr = 0; rr < 4; ++rr) o_acc[nt][rr] *= alpha[rr];
    // O += P V
#pragma unroll
    for (int c = 0; c < 2; ++c) {
      s16x8 pf = *(const s16x8*)(&P_sm[w][m16 * 72 + 8 * g + 32 * c]);
      int kv2 = (8 * g + 32 * c) * 2;
#pragma unroll
      for (int nt = 0; nt < 4; ++nt) {
        int d = m16 + 16 * nt;
        s16x8 vf = *(const s16x8*)((const char*)V_sm + cur * 8192 +
                                   ((d * 128 + kv2) ^ ((d & 7) << 4)));
        o_acc[nt] = __builtin_amdgcn_mfma_f32_16x16x32_bf16(pf, vf, o_acc[nt], 0, 0, 0);
      }
    }
    WAITL0(); BAR(); FENCE();
  }

  // ================= fused output projection =================
  // Z_sm = K_sm[0] (bf16 z, dead after af read); WO_sm = V_sm (2x8 KB);
  // bo_lds = P_sm (3 KB); obuf = K_sm (16 KB f32, alive during nc loop).
  short* Z_sm = (short*)K_sm;
  char* WO_sm = (char*)V_sm;
  float* bo_lds = (float*)P_sm;
  float* obuf = (float*)K_sm;
  const short* wos = wot + (size_t)h * DM * DH;  // [768 m][64 d]

#define STAGE_WO(sel, nc)                                                            \
  do {                                                                               \
    _Pragma("unroll") for (int i = 0; i < 2; ++i) {                                  \
      int ch = w * 2 + i;                                                            \
      int row = ch * 8 + (l >> 3);                                                   \
      GLD_LDS16(wos + (size_t)((nc) * 64 + row) * DH + swz_src,                      \
                WO_sm + (sel) * 8192 + ch * 1024);                                   \
    }                                                                                \
  } while (0)

  STAGE_WO(0, 0);
  // bias table (b_O/H) -> LDS
  for (int i = tid; i < DM; i += 256) bo_lds[i] = bo[i] * (1.0f / 12.0f);
  // z -> Z_sm (swizzled), z = o/l
#pragma unroll
  for (int nt = 0; nt < 4; ++nt) {
#pragma unroll
    for (int rr = 0; rr < 4; ++rr) {
      int row = 16 * w + 4 * g + rr;  // q local
      int d = 16 * nt + m16;
      int byte = (row * 128 + d * 2) ^ ((row & 7) << 4);
      *(short*)((char*)Z_sm + byte) = f2bf(o_acc[nt][rr] / l_run[rr]);
    }
  }
  WAITL0(); BAR(); FENCE();

  s16x8 af[2];
#pragma unroll
  for (int c = 0; c < 2; ++c) {
    int row = 16 * w + m16;
    int kr2 = (8 * g + 32 * c) * 2;
    af[c] = *(const s16x8*)((const char*)Z_sm + ((row * 128 + kr2) ^ ((row & 7) << 4)));
  }
  WAITL0(); BAR(); FENCE();  // af in regs; K_sm region now free for obuf

#pragma unroll
  for (int nc = 0; nc < 12; ++nc) {
    const int cur = nc & 1;
    if (nc < 11) {
      STAGE_WO(cur ^ 1, nc + 1);
      if (nc == 0) { WAITV(2); }  // W0 landed; W1 stays
      else        { WAITV(6); }   // W(nc) landed; stores(nc-1)+W(nc+1) stay
    } else {
      WAITV(4);                   // W11 landed; stores(10) stay
    }
    BAR(); FENCE();
    f32x4 acc2[4];
#pragma unroll
    for (int nt = 0; nt < 4; ++nt) acc2[nt] = zero4();
#pragma unroll
    for (int c = 0; c < 2; ++c) {
      int kr2 = (8 * g + 32 * c) * 2;
#pragma unroll
      for (int nt = 0; nt < 4; ++nt) {
        int row = m16 + 16 * nt;  // m local
        s16x8 bf = *(const s16x8*)(WO_sm + cur * 8192 +
                                   ((row * 128 + kr2) ^ ((row & 7) << 4)));
        acc2[nt] = __builtin_amdgcn_mfma_f32_16x16x32_bf16(af[c], bf, acc2[nt], 0, 0, 0);
      }
    }
    // acc2 (+bias) -> swizzled obuf [64 q][64 m] f32
#pragma unroll
    for (int nt = 0; nt < 4; ++nt) {
#pragma unroll
      for (int rr = 0; rr < 4; ++rr) {
        int ql = 16 * w + 4 * g + rr;
        int ml = 16 * nt + m16;
        int sw = ((ql >> 2) & 3) << 4;
        obuf[ql * 64 + (ml ^ sw)] = acc2[nt][rr] + bo_lds[nc * 64 + ml];
      }
    }
    WAITL0(); BAR(); FENCE();
    // vectorized store: read un-swizzles obuf; GLOBAL DEST IS LINEAR.
    // 16 lanes cover one q-row's 256 B contiguously.
#pragma unroll
    for (int s = 0; s < 4; ++s) {
      int idx = tid + 256 * s;
      int row = idx >> 4;       // q local 0..63
      int ms = idx & 15;
      int sw = ((row >> 2) & 3) << 4;
      f32x4 v = *(const f32x4*)(obuf + row * 64 + ((ms * 4) ^ sw));
      *(f32x4*)(out + ((size_t)(b * S + q0 + row) * H + h) * DM + nc * 64 + ms * 4) = v;
    }
    WAITL0(); BAR(); FENCE();
  }
#undef STAGE_WO
#undef ATTN_STAGE
}

// ---------------------------------------------------------------------------
extern "C" void kernel_launch(void* const* d_in, const int* in_sizes, int n_in,
                              void* d_out, int out_size, void* d_ws, size_t ws_size,
                              hipStream_t stream) {
  const float* xq = (const float*)d_in[0];
  const float* xk = (const float*)d_in[1];
  const float* xv = (const float*)d_in[2];
  const float* wq = (const float*)d_in[3];
  const float* bq = (const float*)d_in[4];
  const float* wk = (const float*)d_in[5];
  const float* bk = (const float*)d_in[6];
  const float* wv = (const float*)d_in[7];
  const float* bv = (const float*)d_in[8];
  const float* wo = (const float*)d_in[9];
  const float* bo = (const float*)d_in[10];
  float* out = (float*)d_out;

  short* wt = (short*)d_ws;                                   // 3*H*64*768
  short* wot = wt + (size_t)3 * H * DH * DM;                  // H*768*64
  short* q_ws = wot + (size_t)H * DM * DH;
  short* k_ws = q_ws + (size_t)BATCH * H * S * DH;
  short* vt_ws = k_ws + (size_t)BATCH * H * S * DH;

  k_prep<<<dim3(1024), dim3(256), 0, stream>>>(wq, wk, wv, wo, wt, wot);
  k_proj<<<dim3(2304), dim3(256), 0, stream>>>(xq, xk, xv, bq, bk, bv, wt, q_ws, k_ws, vt_ws);
  k_attn_o<<<dim3(768), dim3(256), 0, stream>>>(q_ws, k_ws, vt_ws, wot, bo, out);
}

// Round 11
// 219.110 us; speedup vs baseline: 1.0271x; 1.0271x over previous
//
#include <hip/hip_runtime.h>
#include <hip/hip_bf16.h>
#include <stdint.h>

#define H 12
#define S 2048
#define BATCH 2
#define DM 768
#define DH 64

typedef __attribute__((ext_vector_type(4))) float f32x4;
typedef __attribute__((ext_vector_type(4))) short s16x4;
typedef __attribute__((ext_vector_type(8))) short s16x8;

static __device__ __forceinline__ short f2bf(float f) {
  uint32_t u = __builtin_bit_cast(uint32_t, f);
  uint32_t r = (u + 0x7FFFu + ((u >> 16) & 1u)) >> 16;
  return (short)r;
}

static __device__ __forceinline__ s16x8 cvt8(f32x4 a, f32x4 b) {
  s16x8 r;
  r[0] = f2bf(a[0]); r[1] = f2bf(a[1]); r[2] = f2bf(a[2]); r[3] = f2bf(a[3]);
  r[4] = f2bf(b[0]); r[5] = f2bf(b[1]); r[6] = f2bf(b[2]); r[7] = f2bf(b[3]);
  return r;
}

static __device__ __forceinline__ f32x4 zero4() {
  f32x4 v; v[0] = 0.f; v[1] = 0.f; v[2] = 0.f; v[3] = 0.f; return v;
}

#define GLD_LDS16(g, l)                                                              \
  __builtin_amdgcn_global_load_lds((__attribute__((address_space(1))) const void*)(g), \
                                   (__attribute__((address_space(3))) void*)(l), 16, 0, 0)

#define WAITV(N) asm volatile("s_waitcnt vmcnt(" #N ")" ::: "memory")
#define WAITL0() asm volatile("s_waitcnt lgkmcnt(0)" ::: "memory")
#define BAR() __builtin_amdgcn_s_barrier()
#define FENCE() asm volatile("" ::: "memory")
#define PRIO(N) __builtin_amdgcn_s_setprio(N)

// ---------------------------------------------------------------------------
// Kernel 0: weights -> bf16, transposed.
// wt  : [3][H][64 n][768 k]  (W_{Q,K,V}^T per head)
// wot : [H][768 m][64 d]     (W_O^T per head)
// ---------------------------------------------------------------------------
__global__ __launch_bounds__(256) void k_prep(const float* __restrict__ wq,
                                              const float* __restrict__ wk,
                                              const float* __restrict__ wv,
                                              const float* __restrict__ wo,
                                              short* __restrict__ wt,
                                              short* __restrict__ wot) {
  int tid = blockIdx.x * 256 + threadIdx.x;
  int nthr = gridDim.x * 256;
  const int NQKV = 3 * H * DM * DH;
  for (int i = tid; i < NQKV; i += nthr) {
    int n = i & 63;
    int k = (i >> 6) % DM;
    int rest = (i >> 6) / DM;  // t*H + h
    int h = rest % H;
    int t = rest / H;
    const float* src = (t == 0 ? wq : t == 1 ? wk : wv);
    float v = src[((size_t)h * DM + k) * DH + n];
    wt[(((size_t)t * H + h) * DH + n) * DM + k] = f2bf(v);
  }
  const int NO = H * DH * DM;
  for (int i = tid; i < NO; i += nthr) {
    int m = i % DM;
    int d = (i / DM) % DH;
    int h = i / (DM * DH);
    wot[((size_t)h * DM + m) * DH + d] = f2bf(wo[((size_t)h * DH + d) * DM + m]);
  }
}

// ---------------------------------------------------------------------------
// Kernel 1: Q/K/V projection — R5 body, region-co-scheduled mapping (R8 best).
// ---------------------------------------------------------------------------
__global__ __launch_bounds__(256) void k_proj(
    const float* __restrict__ xq, const float* __restrict__ xk, const float* __restrict__ xv,
    const float* __restrict__ bq, const float* __restrict__ bk, const float* __restrict__ bv,
    const short* __restrict__ wt,
    short* __restrict__ q_ws, short* __restrict__ k_ws, short* __restrict__ vt_ws) {
  const int u = blockIdx.x;             // 0..2303
  const int xcd = u & 7;
  const int slot = u >> 3;              // 0..287
  const int r = (slot / 12) * 8 + xcd;  // 0..191 region (t,b,qtile)
  const int h = slot % 12;
  const int t = r / 64;
  const int rb = r % 64;
  const int b = rb >> 5;
  const int q0 = (rb & 31) * 64;

  const float* x = (t == 0 ? xq : t == 1 ? xk : xv);
  const float* xbase = x + ((size_t)(b * S + q0) * H + h) * DM;     // row stride H*DM
  const short* wbase = wt + ((size_t)t * H + h) * (size_t)DH * DM;  // [64 n][768 k]

  __shared__ float A_sm[2][64 * 64];  // 16 KB/half, swizzled content
  __shared__ short W_sm[2][64 * 64];  // 8 KB/half, swizzled content

  const int tid = threadIdx.x;
  const int w = tid >> 6;
  const int l = tid & 63;
  const int g = l >> 4;
  const int m16 = l & 15;
  const int wswz = ((l & 7) ^ (l >> 3)) * 8;  // W source col (shorts)

  const int arow_st = (l >> 4);
  const int apb = (l & 15) * 16;

  f32x4 acc[4];
#pragma unroll
  for (int nt = 0; nt < 4; ++nt) acc[nt] = zero4();

#define PROJ_STAGE(sel, kc)                                                          \
  do {                                                                               \
    _Pragma("unroll") for (int i = 0; i < 4; ++i) {                                  \
      int row = (w * 4 + i) * 4 + arow_st;                                           \
      int colf = (apb ^ ((row & 7) << 4)) >> 2;                                      \
      GLD_LDS16(xbase + (size_t)row * (H * DM) + (kc) * 64 + colf,                   \
                (char*)A_sm + (sel) * 16384 + (w * 4 + i) * 1024);                   \
    }                                                                                \
    _Pragma("unroll") for (int i = 0; i < 2; ++i) {                                  \
      int ch = w * 2 + i;                                                            \
      int n = ch * 8 + (l >> 3);                                                     \
      GLD_LDS16(wbase + (size_t)n * DM + (kc) * 64 + wswz,                           \
                (char*)W_sm + (sel) * 8192 + ch * 1024);                             \
    }                                                                                \
  } while (0)

#define PROJ_COMPUTE(sel)                                                            \
  do {                                                                               \
    const char* Ab = (const char*)A_sm + (sel) * 16384;                              \
    const char* Wb = (const char*)W_sm + (sel) * 8192;                               \
    int arow = 16 * w + m16;                                                         \
    int asw = (arow & 7) << 4;                                                       \
    _Pragma("unroll") for (int c = 0; c < 2; ++c) {                                  \
      f32x4 a0 = *(const f32x4*)(Ab + arow * 256 + ((32 * g + 128 * c) ^ asw));      \
      f32x4 a1 = *(const f32x4*)(Ab + arow * 256 + ((32 * g + 128 * c + 16) ^ asw)); \
      s16x8 afr = cvt8(a0, a1);                                                      \
      int krow = 8 * g + 32 * c;                                                     \
      PRIO(1);                                                                       \
      _Pragma("unroll") for (int nt = 0; nt < 4; ++nt) {                             \
        int n = m16 + 16 * nt;                                                       \
        s16x8 bfr = *(const s16x8*)(Wb + ((n * 128 + krow * 2) ^ ((n & 7) << 4)));   \
        acc[nt] = __builtin_amdgcn_mfma_f32_16x16x32_bf16(afr, bfr, acc[nt], 0, 0, 0); \
      }                                                                              \
      PRIO(0);                                                                       \
    }                                                                                \
  } while (0)

  PROJ_STAGE(0, 0);  // 6 vmem in flight
#pragma unroll
  for (int kc = 0; kc < 12; ++kc) {
    const int cur = kc & 1;
    if (kc < 11) {
      PROJ_STAGE(cur ^ 1, kc + 1);
      WAITV(6);  // chunk kc landed; chunk kc+1 stays in flight
    } else {
      WAITV(0);
    }
    BAR(); FENCE();
    PROJ_COMPUTE(cur);
    WAITL0(); BAR(); FENCE();
  }

  const float* bias = (t == 0 ? bq : t == 1 ? bk : bv) + h * DH;
  if (t < 2) {
    short* dst = (t == 0 ? q_ws : k_ws) + (size_t)(b * H + h) * S * DH;
#pragma unroll
    for (int nt = 0; nt < 4; ++nt) {
      int n = 16 * nt + m16;
      float bb = bias[n];
#pragma unroll
      for (int r2 = 0; r2 < 4; ++r2) {
        int q = q0 + 16 * w + 4 * g + r2;
        dst[(size_t)q * DH + n] = f2bf(acc[nt][r2] + bb);
      }
    }
  } else {
    short* dst = vt_ws + (size_t)(b * H + h) * DH * S;  // [d][kv]
#pragma unroll
    for (int nt = 0; nt < 4; ++nt) {
      int n = 16 * nt + m16;  // d
      float bb = bias[n];
#pragma unroll
      for (int r2 = 0; r2 < 4; ++r2) {
        int q = q0 + 16 * w + 4 * g + r2;  // kv
        dst[(size_t)n * S + q] = f2bf(acc[nt][r2] + bb);
      }
    }
  }
}

// ---------------------------------------------------------------------------
// Kernel 2: causal flash attention FUSED with output projection (R8 epilogue,
// direct stores) + T5 setprio around MFMA clusters.
// ---------------------------------------------------------------------------
__global__ __launch_bounds__(256) void k_attn_o(const short* __restrict__ q_ws,
                                                const short* __restrict__ k_ws,
                                                const short* __restrict__ vt_ws,
                                                const short* __restrict__ wot,
                                                const float* __restrict__ bo,
                                                float* __restrict__ out) {
  const int u = blockIdx.x;         // 0..767
  const int xcd = u & 7;
  const int slot = u >> 3;          // 0..95
  const int r = (slot / 12) * 8 + xcd;  // 0..63 region (b,qtile)
  const int h = slot % 12;
  const int b = r >> 5;
  const int qtile = 31 - (r & 31);  // heavy (late) q-tiles first
  const int q0 = qtile * 64;

  const size_t sl = (size_t)(b * H + h) * S * DH;
  const short* qs = q_ws + sl;
  const short* ks = k_ws + sl;
  const short* vs = vt_ws + sl;  // [64 d][2048 kv]

  __shared__ short K_sm[2][64 * 64];
  __shared__ short V_sm[2][64 * 64];
  __shared__ short P_sm[4][16 * 72];

  const int tid = threadIdx.x;
  const int w = tid >> 6;
  const int l = tid & 63;
  const int g = l >> 4;
  const int m16 = l & 15;
  const int swz_src = ((l & 7) ^ (l >> 3)) * 8;

#define ATTN_STAGE(sel, kv0)                                                         \
  do {                                                                               \
    _Pragma("unroll") for (int i = 0; i < 2; ++i) {                                  \
      int ch = w * 2 + i;                                                            \
      int row = ch * 8 + (l >> 3);                                                   \
      GLD_LDS16(ks + (size_t)((kv0) + row) * DH + swz_src,                           \
                (char*)K_sm + (sel) * 8192 + ch * 1024);                             \
      GLD_LDS16(vs + (size_t)row * S + (kv0) + swz_src,                              \
                (char*)V_sm + (sel) * 8192 + ch * 1024);                             \
    }                                                                                \
  } while (0)

  s16x8 qf[2];
  {
    int q = q0 + 16 * w + m16;
    qf[0] = *(const s16x8*)(qs + (size_t)q * DH + 8 * g);
    qf[1] = *(const s16x8*)(qs + (size_t)q * DH + 8 * g + 32);
  }

  f32x4 o_acc[4];
  float m_run[4], l_run[4], alpha[4];
#pragma unroll
  for (int nt = 0; nt < 4; ++nt) o_acc[nt] = zero4();
#pragma unroll
  for (int rr = 0; rr < 4; ++rr) { m_run[rr] = -3.0e38f; l_run[rr] = 0.f; }

  const int ktiles = qtile + 1;
  ATTN_STAGE(0, 0);  // 4 in flight
  for (int kt = 0; kt < ktiles; ++kt) {
    const int kv0 = kt * 64;
    const int cur = kt & 1;
    if (kt + 1 < ktiles) {
      ATTN_STAGE(cur ^ 1, kv0 + 64);
      WAITV(4);
    } else {
      WAITV(0);
    }
    BAR(); FENCE();

    // S = Q K^T
    f32x4 sacc[4];
#pragma unroll
    for (int nt = 0; nt < 4; ++nt) sacc[nt] = zero4();
    PRIO(1);
#pragma unroll
    for (int c = 0; c < 2; ++c) {
      int kr2 = (8 * g + 32 * c) * 2;
#pragma unroll
      for (int nt = 0; nt < 4; ++nt) {
        int row = m16 + 16 * nt;  // kv local
        s16x8 kf = *(const s16x8*)((const char*)K_sm + cur * 8192 +
                                   ((row * 128 + kr2) ^ ((row & 7) << 4)));
        sacc[nt] = __builtin_amdgcn_mfma_f32_16x16x32_bf16(qf[c], kf, sacc[nt], 0, 0, 0);
      }
    }
    PRIO(0);
    // scale + causal mask
    float sv[4][4];
#pragma unroll
    for (int nt = 0; nt < 4; ++nt) {
      int kv = kv0 + 16 * nt + m16;
#pragma unroll
      for (int rr = 0; rr < 4; ++rr) {
        int q = q0 + 16 * w + 4 * g + rr;
        float s = sacc[nt][rr] * 0.125f;
        sv[nt][rr] = (kv > q) ? -1.0e30f : s;
      }
    }
    // online softmax
#pragma unroll
    for (int rr = 0; rr < 4; ++rr) {
      float tm = fmaxf(fmaxf(sv[0][rr], sv[1][rr]), fmaxf(sv[2][rr], sv[3][rr]));
      tm = fmaxf(tm, __shfl_xor(tm, 1));
      tm = fmaxf(tm, __shfl_xor(tm, 2));
      tm = fmaxf(tm, __shfl_xor(tm, 4));
      tm = fmaxf(tm, __shfl_xor(tm, 8));
      float mn = fmaxf(m_run[rr], tm);
      alpha[rr] = __expf(m_run[rr] - mn);
      m_run[rr] = mn;
      float rs = 0.f;
#pragma unroll
      for (int nt = 0; nt < 4; ++nt) {
        float p = __expf(sv[nt][rr] - mn);
        sv[nt][rr] = p;
        rs += p;
      }
      rs += __shfl_xor(rs, 1);
      rs += __shfl_xor(rs, 2);
      rs += __shfl_xor(rs, 4);
      rs += __shfl_xor(rs, 8);
      l_run[rr] = l_run[rr] * alpha[rr] + rs;
    }
    // P -> bf16 -> per-wave LDS bounce
#pragma unroll
    for (int nt = 0; nt < 4; ++nt)
#pragma unroll
      for (int rr = 0; rr < 4; ++rr)
        P_sm[w][(4 * g + rr) * 72 + 16 * nt + m16] = f2bf(sv[nt][rr]);
    // rescale O
#pragma unroll
    for (int nt = 0; nt < 4; ++nt)
#pragma unroll
      for (int rr = 0; rr < 4; ++rr) o_acc[nt][rr] *= alpha[rr];
    // O += P V
#pragma unroll
    for (int c = 0; c < 2; ++c) {
      s16x8 pf = *(const s16x8*)(&P_sm[w][m16 * 72 + 8 * g + 32 * c]);
      int kv2 = (8 * g + 32 * c) * 2;
      PRIO(1);
#pragma unroll
      for (int nt = 0; nt < 4; ++nt) {
        int d = m16 + 16 * nt;
        s16x8 vf = *(const s16x8*)((const char*)V_sm + cur * 8192 +
                                   ((d * 128 + kv2) ^ ((d & 7) << 4)));
        o_acc[nt] = __builtin_amdgcn_mfma_f32_16x16x32_bf16(pf, vf, o_acc[nt], 0, 0, 0);
      }
      PRIO(0);
    }
    WAITL0(); BAR(); FENCE();
  }

  // ================= fused output projection (R8 epilogue) =================
  // LDS reuse: Z_sm = K_sm (8 KB), WO_sm = V_sm (2x8 KB), bo_lds = P_sm (3 KB)
  short* Z_sm = (short*)K_sm;
  char* WO_sm = (char*)V_sm;
  float* bo_lds = (float*)P_sm;
  const short* wos = wot + (size_t)h * DM * DH;  // [768 m][64 d]

#define STAGE_WO(sel, nc)                                                            \
  do {                                                                               \
    _Pragma("unroll") for (int i = 0; i < 2; ++i) {                                  \
      int ch = w * 2 + i;                                                            \
      int row = ch * 8 + (l >> 3);                                                   \
      GLD_LDS16(wos + (size_t)((nc) * 64 + row) * DH + swz_src,                      \
                WO_sm + (sel) * 8192 + ch * 1024);                                   \
    }                                                                                \
  } while (0)

  STAGE_WO(0, 0);  // hide under Z/bias staging
  // bias table (b_O/H) -> LDS
  for (int i = tid; i < DM; i += 256) bo_lds[i] = bo[i] * (1.0f / 12.0f);
  // z -> Z_sm (swizzled), z = o/l
#pragma unroll
  for (int nt = 0; nt < 4; ++nt) {
#pragma unroll
    for (int rr = 0; rr < 4; ++rr) {
      int row = 16 * w + 4 * g + rr;              // q local
      int d = 16 * nt + m16;
      int byte = (row * 128 + d * 2) ^ ((row & 7) << 4);
      *(short*)((char*)Z_sm + byte) = f2bf(o_acc[nt][rr] / l_run[rr]);
    }
  }
  WAITL0(); BAR(); FENCE();

  s16x8 af[2];
#pragma unroll
  for (int c = 0; c < 2; ++c) {
    int row = 16 * w + m16;
    int kr2 = (8 * g + 32 * c) * 2;
    af[c] = *(const s16x8*)((const char*)Z_sm + ((row * 128 + kr2) ^ ((row & 7) << 4)));
  }

#pragma unroll
  for (int nc = 0; nc < 12; ++nc) {
    const int cur = nc & 1;
    if (nc < 11) {
      STAGE_WO(cur ^ 1, nc + 1);
      if (nc == 0) { WAITV(2); }   // only glds outstanding
      else        { WAITV(18); }   // 16 stores(prev) + 2 glds newest
    } else {
      WAITV(0);
    }
    BAR(); FENCE();
    f32x4 acc[4];
#pragma unroll
    for (int nt = 0; nt < 4; ++nt) acc[nt] = zero4();
    PRIO(1);
#pragma unroll
    for (int c = 0; c < 2; ++c) {
      int kr2 = (8 * g + 32 * c) * 2;
#pragma unroll
      for (int nt = 0; nt < 4; ++nt) {
        int row = m16 + 16 * nt;  // m local
        s16x8 bf = *(const s16x8*)(WO_sm + cur * 8192 +
                                   ((row * 128 + kr2) ^ ((row & 7) << 4)));
        acc[nt] = __builtin_amdgcn_mfma_f32_16x16x32_bf16(af[c], bf, acc[nt], 0, 0, 0);
      }
    }
    PRIO(0);
#pragma unroll
    for (int nt = 0; nt < 4; ++nt) {
      int m = nc * 64 + 16 * nt + m16;
      float bias = bo_lds[m];
#pragma unroll
      for (int rr = 0; rr < 4; ++rr) {
        int q = q0 + 16 * w + 4 * g + rr;
        out[((size_t)(b * S + q) * H + h) * DM + m] = acc[nt][rr] + bias;
      }
    }
    WAITL0(); BAR(); FENCE();
  }
#undef STAGE_WO
#undef ATTN_STAGE
}

// ---------------------------------------------------------------------------
extern "C" void kernel_launch(void* const* d_in, const int* in_sizes, int n_in,
                              void* d_out, int out_size, void* d_ws, size_t ws_size,
                              hipStream_t stream) {
  const float* xq = (const float*)d_in[0];
  const float* xk = (const float*)d_in[1];
  const float* xv = (const float*)d_in[2];
  const float* wq = (const float*)d_in[3];
  const float* bq = (const float*)d_in[4];
  const float* wk = (const float*)d_in[5];
  const float* bk = (const float*)d_in[6];
  const float* wv = (const float*)d_in[7];
  const float* bv = (const float*)d_in[8];
  const float* wo = (const float*)d_in[9];
  const float* bo = (const float*)d_in[10];
  float* out = (float*)d_out;

  short* wt = (short*)d_ws;                                   // 3*H*64*768
  short* wot = wt + (size_t)3 * H * DH * DM;                  // H*768*64
  short* q_ws = wot + (size_t)H * DM * DH;
  short* k_ws = q_ws + (size_t)BATCH * H * S * DH;
  short* vt_ws = k_ws + (size_t)BATCH * H * S * DH;

  k_prep<<<dim3(1024), dim3(256), 0, stream>>>(wq, wk, wv, wo, wt, wot);
  k_proj<<<dim3(2304), dim3(256), 0, stream>>>(xq, xk, xv, bq, bk, bv, wt, q_ws, k_ws, vt_ws);
  k_attn_o<<<dim3(768), dim3(256), 0, stream>>>(q_ws, k_ws, vt_ws, wot, bo, out);
}